// Round 1
// 80.681 us; speedup vs baseline: 1.0084x; 1.0084x over previous
//
#include <hip/hip_runtime.h>
#include <math.h>

typedef unsigned long long u64;

#define H 2048
#define W 2048
#define NWR 64          // word-rows (H/32)
#define TILE 128        // output cols per block
#define HALOC 16        // LDS col halo; reg window d<=8, LDS d<=16, then img walk
#define LW 160          // TILE + 2*HALOC
#define LSTRIDE 161     // 161 % 32 == 1: decode writes and row reads conflict-free
#define DCLAMP 2900     // > max possible distance; f <= 8.41e6 exact in fp32
#define NTHR 256
#define NBLK 1024       // grid (16 x 64) == residency capacity (R15/R17-proven)

#define TAG_V  0x33C0FFEEull   // vcell hi32 tag (0xAA poison can never match)
#define TAG_F  0x44C0FFEEull   // flag  hi32 tag

// ---------------------------------------------------------------------------
// Rare far-paths walk the INPUT img directly (always visible, no ordering
// needed — this is what makes the kernel barrier-free before the max).
// Row halo is now +-16 (64-row u64 window): P(fallback) ~ 2^-16 per pixel-side
// => ~10 cheap walks per image, exactness preserved for arbitrary inputs.
// ---------------------------------------------------------------------------
__device__ __attribute__((noinline)) int vfar_up_img(const float* img, int col, int r, int rtop) {
    for (int rr = rtop - 1; rr >= 0; --rr)
        if (img[(size_t)rr * W + col] <= 0.5f) return r - rr;
    return DCLAMP;
}
__device__ __attribute__((noinline)) int vfar_dn_img(const float* img, int col, int r, int rbot) {
    for (int rr = rbot + 1; rr < H; ++rr)
        if (img[(size_t)rr * W + col] <= 0.5f) return rr - r;
    return DCLAMP;
}
// exact f at arbitrary (r, col) from img (never-taken beyond-halo fallback)
__device__ __attribute__((noinline)) float f_from_img(const float* img, int col, int r) {
    if (img[(size_t)r * W + col] <= 0.5f) return 0.0f;
    int du = DCLAMP, dn = DCLAMP;
    for (int dd = 1; r - dd >= 0; ++dd)
        if (img[(size_t)(r - dd) * W + col] <= 0.5f) { du = dd; break; }
    for (int dd = 1; r + dd < H; ++dd)
        if (img[(size_t)(r + dd) * W + col] <= 0.5f) { dn = dd; break; }
    int d1 = min(min(du, dn), DCLAMP);
    return (float)d1 * (float)d1;
}

// ---------------------------------------------------------------------------
// Single kernel. Block (bx, ks) owns a 128-col x 32-row tile.
// Phase 1: each of 160 threads packs its own column's 64-row img window into
//   ONE u64 (rows rbase-16 .. rbase+47), bit-decodes f = d1^2 for 32 rows
//   into LDS. 64 loads/thread (was 96), no multi-word splicing.
//   Total input reads: 2.5x of img (was 4.5x).
// Phase 2: register sliding-window exact row pass (d<=8 regs; rare d<=16 LDS;
//   never-taken exact img-walk fallback).
// Phase 3: results staged in LDS; block max via shuffle.
// Max barrier: tagged u64 store/poll, ALL RELAXED (R14: no same-address RMW;
//   R16/R17: no release -> no buffer_wbl2). 0xAA ws poison == "not ready".
//   Block 0 now issues all 4 cell loads per spin iteration (parallel misses,
//   not 4 dependent spin loops) to cut serial latency off the critical path.
// Phase 4: normalize from LDS, coalesced int4 store (uint8 semantics).
// Residency: 20.6 KB LDS; launch_bounds(256,4) -> 4/CU; 1024 = grid.
// ---------------------------------------------------------------------------
__global__ void __launch_bounds__(NTHR, 4)
edt_solo(const float* __restrict__ img, int* __restrict__ out,
         u64* __restrict__ vcell, u64* __restrict__ flag) {
    __shared__ float ftile[32][LSTRIDE];   // 20.6 KB
    __shared__ float smax[5];
    const int tid = threadIdx.x;
    const int c0 = blockIdx.x * TILE;
    const int ks = blockIdx.y;
    const int rbase = ks * 32;
    const int bid = ks * (W / TILE) + blockIdx.x;

    // ---- Phase 1: per-column pack (64 rows -> one u64) + decode into LDS
    if (tid < LW) {
        int gc = c0 - HALOC + tid;
        if (gc >= 0 && gc < W) {
            u64 Wv = 0;   // bit b  <=>  row (rbase - 16 + b), b in [0, 64)
            if (ks > 0) {
#pragma unroll
                for (int i = 0; i < 16; ++i)
                    Wv |= (u64)(img[(size_t)(rbase - 16 + i) * W + gc] <= 0.5f) << i;
            }
#pragma unroll
            for (int i = 16; i < 48; ++i)
                Wv |= (u64)(img[(size_t)(rbase - 16 + i) * W + gc] <= 0.5f) << i;
            if (ks < NWR - 1) {
#pragma unroll
                for (int i = 48; i < 64; ++i)
                    Wv |= (u64)(img[(size_t)(rbase - 16 + i) * W + gc] <= 0.5f) << i;
            }
#pragma unroll
            for (int i = 0; i < 32; ++i) {
                const int p = 16 + i;          // bit position of row rbase+i
                u64 lo = Wv & ((1ull << p) - 1ull);
                int da = lo ? (p - (63 - __clzll(lo)))
                            : vfar_up_img(img, gc, rbase + i, rbase - 16);
                u64 hi = Wv >> (p + 1);
                int db = hi ? __ffsll(hi)
                            : vfar_dn_img(img, gc, rbase + i, rbase + 47);
                int d1 = min(min(da, db), DCLAMP);
                float fd = (float)d1;
                ftile[i][tid] = ((Wv >> p) & 1ull) ? 0.0f : fd * fd;
            }
        } else {
#pragma unroll
            for (int i = 0; i < 32; ++i)
                ftile[i][tid] = 1e9f;   // pad: cost >= 1e9 never wins
        }
    }
    __syncthreads();

    // ---- Phase 2: register sliding window (exact)
    const int i  = tid & 31;        // row within tile
    const int p  = tid >> 5;        // 16-col strip
    const int lc = HALOC + p * 16;  // LDS col of first output
    float reg[32];                  // f for LDS cols lc-8 .. lc+23
#pragma unroll
    for (int k = 0; k < 32; ++k)
        reg[k] = ftile[i][lc - 8 + k];

    float res[16];
    float lmax = 0.0f;
#pragma unroll
    for (int m = 0; m < 16; ++m) {
        float best = reg[m + 8];
#pragma unroll
        for (int d = 1; d <= 8; ++d) {
            float q = (float)(d * d);
            best = fminf(best, reg[m + 8 - d] + q);
            best = fminf(best, reg[m + 8 + d] + q);
        }
        if (__builtin_expect(81.0f < best, 0)) {
            for (int d = 9; d <= HALOC && (float)(d * d) < best; ++d) {
                float q = (float)(d * d);
                best = fminf(best, ftile[i][lc + m - d] + q);
                best = fminf(best, ftile[i][lc + m + d] + q);
            }
            if ((float)((HALOC + 1) * (HALOC + 1)) < best) {
                // exact img-walk fallback (never taken for random 50% mask)
                int r = rbase + i, jj = c0 + p * 16 + m;
                for (int d = HALOC + 1; d < W && (float)(d * d) < best; ++d) {
                    float q = (float)(d * d);
                    int jm = jj - d, jp = jj + d;
                    if (jm >= 0) best = fminf(best, f_from_img(img, jm, r) + q);
                    if (jp < W)  best = fminf(best, f_from_img(img, jp, r) + q);
                }
            }
        }
        float rr = sqrtf(best);
        res[m] = rr;
        lmax = fmaxf(lmax, rr);
    }

    // ---- Phase 3: stage res to LDS (stays there across the barrier)
    __syncthreads();   // all ftile reads done
#pragma unroll
    for (int m = 0; m < 16; ++m)
        ftile[i][p * 16 + m] = res[m];

    for (int o = 32; o > 0; o >>= 1) lmax = fmaxf(lmax, __shfl_down(lmax, o, 64));
    if ((tid & 63) == 0) smax[1 + (tid >> 6)] = lmax;
    __syncthreads();

    // ---- Max barrier: tagged u64 store/poll, all RELAXED (no RMW, no wbl2)
    if (tid == 0) {
        float bm = fmaxf(fmaxf(smax[1], smax[2]), fmaxf(smax[3], smax[4]));
        u64 v = (TAG_V << 32) | (u64)__float_as_uint(bm);
        __hip_atomic_store(&vcell[bid], v, __ATOMIC_RELAXED, __HIP_MEMORY_SCOPE_AGENT);
    }
    if (bid == 0) {
        // parallel spin: issue all 4 cell loads each iteration (no dependent
        // sequential spin loops -> one miss latency instead of four)
        u64 v[NBLK / NTHR];
        bool ready;
        do {
            ready = true;
#pragma unroll
            for (int k = 0; k < NBLK / NTHR; ++k)
                v[k] = __hip_atomic_load(&vcell[tid * (NBLK / NTHR) + k],
                                         __ATOMIC_RELAXED, __HIP_MEMORY_SCOPE_AGENT);
#pragma unroll
            for (int k = 0; k < NBLK / NTHR; ++k)
                ready &= ((v[k] >> 32) == TAG_V);
            if (!ready) __builtin_amdgcn_s_sleep(2);
        } while (!ready);
        float mv = 0.0f;
#pragma unroll
        for (int k = 0; k < NBLK / NTHR; ++k)
            mv = fmaxf(mv, __uint_as_float((unsigned)v[k]));
        for (int o = 32; o > 0; o >>= 1) mv = fmaxf(mv, __shfl_down(mv, o, 64));
        if ((tid & 63) == 0) smax[1 + (tid >> 6)] = mv;
        __syncthreads();
        if (tid == 0) {
            float gm = fmaxf(fmaxf(smax[1], smax[2]), fmaxf(smax[3], smax[4]));
            smax[0] = gm;
            u64 v2 = (TAG_F << 32) | (u64)__float_as_uint(gm);
            __hip_atomic_store(flag, v2, __ATOMIC_RELAXED, __HIP_MEMORY_SCOPE_AGENT);
        }
    } else if (tid == 0) {
        u64 v;
        while (((v = __hip_atomic_load(flag, __ATOMIC_RELAXED,
                                       __HIP_MEMORY_SCOPE_AGENT)) >> 32) != TAG_F)
            __builtin_amdgcn_s_sleep(8);
        smax[0] = __uint_as_float((unsigned)v);
    }
    __syncthreads();

    // ---- Phase 4: normalize from LDS, coalesced int4 store (uint8 semantics)
    float m = smax[0];
    float scale = (m > 0.0f) ? 1.0f / m : 0.0f;
#pragma unroll
    for (int q = 0; q < 4; ++q) {
        int r  = (tid >> 5) + 8 * q;      // 0..31
        int c4 = (tid & 31) * 4;
        int o[4];
#pragma unroll
        for (int k = 0; k < 4; ++k) {
            float dv = ftile[r][c4 + k];
            float v = (m > 0.0f) ? (dv * scale * 255.0f) : dv;
            v = fminf(fmaxf(v, 0.0f), 255.0f);
            o[k] = (int)v;                // trunc, like astype(uint8)
        }
        *(int4*)(out + (size_t)(rbase + r) * W + c0 + c4) = make_int4(o[0], o[1], o[2], o[3]);
    }
}

extern "C" void kernel_launch(void* const* d_in, const int* in_sizes, int n_in,
                              void* d_out, int out_size, void* d_ws, size_t ws_size,
                              hipStream_t stream) {
    const float* img = (const float*)d_in[0];
    int* out = (int*)d_out;

    // ws: vcell[1024] u64 | flag u64 (own cache line). No init kernel needed:
    // harness poisons ws to 0xAA before every launch; tags treat that as "not ready".
    u64* vcell = (u64*)d_ws;
    u64* flag  = (u64*)((char*)d_ws + 8192 + 128);

    edt_solo<<<dim3(W / TILE, NWR), dim3(NTHR), 0, stream>>>(img, out, vcell, flag);
}